// Round 9
// baseline (3944.211 us; speedup 1.0000x reference)
//
#include <hip/hip_runtime.h>
#include <hip/hip_bf16.h>
#include <hip/hip_fp16.h>
#include <math.h>

#define BB 256
#define TT 256
// H=[128,32,32], TH=192, ZDIM=64, ATT=4

__device__ __forceinline__ float sigf(float x) { return 1.f / (1.f + expf(-x)); }

typedef _Float16 half8v __attribute__((ext_vector_type(8)));
typedef _Float16 half2v __attribute__((ext_vector_type(2)));

// Paired dot: weights in [k/2][2N] interleave — wv0/wv1 = 8 outputs x k-pair.
// f16xf16 products are exact in f32; accumulation stays f32.
__device__ __forceinline__ void dot8p(float (&acc)[8], float4 wv0, float4 wv1,
                                      float a0, float a1) {
#if __has_builtin(__builtin_amdgcn_fdot2)
    const half2v ap = __builtin_bit_cast(half2v, __builtin_amdgcn_cvt_pkrtz(a0, a1));
    acc[0] = __builtin_amdgcn_fdot2(__builtin_bit_cast(half2v, wv0.x), ap, acc[0], false);
    acc[1] = __builtin_amdgcn_fdot2(__builtin_bit_cast(half2v, wv0.y), ap, acc[1], false);
    acc[2] = __builtin_amdgcn_fdot2(__builtin_bit_cast(half2v, wv0.z), ap, acc[2], false);
    acc[3] = __builtin_amdgcn_fdot2(__builtin_bit_cast(half2v, wv0.w), ap, acc[3], false);
    acc[4] = __builtin_amdgcn_fdot2(__builtin_bit_cast(half2v, wv1.x), ap, acc[4], false);
    acc[5] = __builtin_amdgcn_fdot2(__builtin_bit_cast(half2v, wv1.y), ap, acc[5], false);
    acc[6] = __builtin_amdgcn_fdot2(__builtin_bit_cast(half2v, wv1.z), ap, acc[6], false);
    acc[7] = __builtin_amdgcn_fdot2(__builtin_bit_cast(half2v, wv1.w), ap, acc[7], false);
#else
    half8v h0 = __builtin_bit_cast(half8v, wv0);
    half8v h1 = __builtin_bit_cast(half8v, wv1);
#pragma unroll
    for (int m = 0; m < 4; ++m) acc[m]     += (float)h0[2*m] * a0 + (float)h0[2*m+1] * a1;
#pragma unroll
    for (int m = 0; m < 4; ++m) acc[4 + m] += (float)h1[2*m] * a0 + (float)h1[2*m+1] * a1;
#endif
}

// lgkm-only barrier: drains LDS ops; global loads stay in flight across it.
#define BAR() do {                                   \
    __atomic_signal_fence(__ATOMIC_SEQ_CST);         \
    __builtin_amdgcn_s_waitcnt(0xC07F);              \
    __builtin_amdgcn_s_barrier();                    \
    __atomic_signal_fence(__ATOMIC_SEQ_CST);         \
} while (0)

// f32 [K][N] -> f16 paired layout: (k,j) -> (k>>1)*2N + 2j + (k&1).
__global__ void f2h_pair(const float* __restrict__ s, __half* __restrict__ d,
                         int K, int N) {
    int i = blockIdx.x * 256 + threadIdx.x;
    if (i < K * N) {
        int k = i / N, j = i - k * N;
        d[(size_t)(k >> 1) * (2 * N) + 2 * j + (k & 1)] = __float2half(s[i]);
    }
}

// ---------------------------------------------------------------------------
// Kernel 1: G = X @ W + bias
// ---------------------------------------------------------------------------
#define GT_M 128
#define GT_N 64
#define GT_K 16

__device__ __forceinline__ void stvec4(float* p, float4 v) { *(float4*)p = v; }
__device__ __forceinline__ void stvec4(__half* p, float4 v) {
    *(__half2*)p = __floats2half2_rn(v.x, v.y);
    *(__half2*)(p + 2) = __floats2half2_rn(v.z, v.w);
}

template <typename OT>
__global__ __launch_bounds__(256)
void xw_gemm(const float* __restrict__ X, const float* __restrict__ W,
             const float* __restrict__ bias, OT* __restrict__ G,
             int M, int N, int K) {
    __shared__ float As[GT_K][GT_M + 4];
    __shared__ float Bs[GT_K][GT_N];
    const int tid = threadIdx.x;
    const int bm = blockIdx.y * GT_M;
    const int bn = blockIdx.x * GT_N;
    const int tx = tid & 15;
    const int ty = tid >> 4;

    float acc[8][4];
#pragma unroll
    for (int i = 0; i < 8; ++i)
#pragma unroll
        for (int j = 0; j < 4; ++j) acc[i][j] = 0.f;

    for (int kt = 0; kt < K; kt += GT_K) {
#pragma unroll
        for (int i = 0; i < 8; ++i) {
            int idx = i * 256 + tid;
            int m = idx >> 4, k = idx & 15;
            int gk = kt + k;
            As[k][m] = (gk < K) ? X[(size_t)(bm + m) * K + gk] : 0.f;
        }
#pragma unroll
        for (int i = 0; i < 4; ++i) {
            int idx = i * 256 + tid;
            int k = idx >> 6, n = idx & 63;
            int gk = kt + k;
            Bs[k][n] = (gk < K) ? W[(size_t)gk * N + bn + n] : 0.f;
        }
        __syncthreads();
#pragma unroll
        for (int k = 0; k < GT_K; ++k) {
            float a[8], b[4];
            const float4 a0 = *(const float4*)&As[k][ty * 8];
            const float4 a1 = *(const float4*)&As[k][ty * 8 + 4];
            const float4 bv = *(const float4*)&Bs[k][tx * 4];
            a[0]=a0.x; a[1]=a0.y; a[2]=a0.z; a[3]=a0.w;
            a[4]=a1.x; a[5]=a1.y; a[6]=a1.z; a[7]=a1.w;
            b[0]=bv.x; b[1]=bv.y; b[2]=bv.z; b[3]=bv.w;
#pragma unroll
            for (int i = 0; i < 8; ++i)
#pragma unroll
                for (int j = 0; j < 4; ++j) acc[i][j] += a[i] * b[j];
        }
        __syncthreads();
    }
    const int n0 = bn + tx * 4;
#pragma unroll
    for (int i = 0; i < 8; ++i) {
        int m = bm + ty * 8 + i;
        float4 v;
        v.x = acc[i][0] + bias[n0 + 0];
        v.y = acc[i][1] + bias[n0 + 1];
        v.z = acc[i][2] + bias[n0 + 2];
        v.w = acc[i][3] + bias[n0 + 3];
        stvec4(&G[(size_t)m * N + n0], v);
    }
}

// ---------------------------------------------------------------------------
// Kernel 2: persistent recurrence. 256 blocks x 1024 threads, 1 row/block.
// r9: 16 waves/CU (was 8). r8's phase-shuffle was reverted (neutral-negative:
// streams are byte-bound per phase, not phase-placement-bound). The att2
// phase (393KB, the dominant stream) is split 2x wider: 768 threads x 16
// k-pairs (8 chunks) -> double wave-level load parallelism to lift the
// latency-limited effective L2 rate. All other phases byte-identical to r7.
// VGPR cap at 16 waves/CU is 128; per-thread code unchanged (~116) -> fits.
// r5: block-staggered k-rotation. r6/7: fdot2 paired layout.
// att1 weights (96KB) + cw11/cw12 (16KB) pinned in LDS (paired layout).
// ---------------------------------------------------------------------------
__global__ __launch_bounds__(1024, 1)
void marn_rec(const float* __restrict__ G0, const __half* __restrict__ G1h,
              const __half* __restrict__ G2h,
              const __half* __restrict__ hU0, const __half* __restrict__ hV0,
              const __half* __restrict__ hU1, const __half* __restrict__ hV1,
              const __half* __restrict__ hU2, const __half* __restrict__ hV2,
              const __half* __restrict__ haw1, const float* __restrict__ ab1,
              const __half* __restrict__ haw2, const float* __restrict__ ab2,
              const __half* __restrict__ hcw10, const float* __restrict__ cb10,
              const float* __restrict__ cw20, const float* __restrict__ cb20,
              const __half* __restrict__ hcw11, const float* __restrict__ cb11,
              const float* __restrict__ cw21, const float* __restrict__ cb21,
              const __half* __restrict__ hcw12, const float* __restrict__ cb12,
              const float* __restrict__ cw22, const float* __restrict__ cb22,
              const float* __restrict__ fw1, const float* __restrict__ fb1,
              const float* __restrict__ fw2, const float* __restrict__ fb2,
              float* __restrict__ out) {
    __shared__ float hz[256];     // [h0(128)|h1(32)|h2(32)|z(64)]
    __shared__ float cst[192];
    __shared__ float a1s[256];
    __shared__ float attE[768];
    __shared__ float hid[128];
    __shared__ float rinv[4];     // reciprocal softmax denominators
    __shared__ float scratch[6144];  // max user: att2 (8 chunks x 768)
    __shared__ float c2w[3072];   // cw20(2048)|cw21(512)|cw22(512)
    __shared__ __align__(16) __half s_aw1[49152];  // att1 weights, paired, pinned
    __shared__ __align__(16) __half s_c1b[8192];   // cw11(4096)|cw12(4096), paired

    const int tid = threadIdx.x;
    const int row = blockIdx.x;
    // de-contention rotation offsets, in k-PAIRS (r5 mechanism)
    const int rotPA = ((row >> 3) & 3) * 4;   // stage A: 16 pairs
    const int rotPB = ((row >> 3) & 3) * 4;   // att2:    16 pairs per chunk
    const int rotPC = ((row >> 3) & 3) * 4;   // comp1:   16 pairs

    for (int i = tid; i < 256; i += 1024) hz[i] = 0.f;
    if (tid < 192) cst[tid] = 0.f;
    for (int i = tid; i < 2048; i += 1024) c2w[i] = cw20[i];
    if (tid < 512) { c2w[2048 + tid] = cw21[tid]; c2w[2560 + tid] = cw22[tid]; }
    {
        const float4* s4 = (const float4*)haw1;
        float4* d4 = (float4*)s_aw1;
        for (int i = tid; i < 6144; i += 1024) d4[i] = s4[i];
        if (tid < 512) {
            float4* d1 = (float4*)s_c1b;
            d1[tid] = ((const float4*)hcw11)[tid];
            d1[512 + tid] = ((const float4*)hcw12)[tid];
        }
    }
    __syncthreads();

    // ---- stage A mapping (480 active), paired layout (as r7) ----
    const __half* WBa = nullptr; int HOa = 0, STRa = 0, SOa = 0;
    if (tid < 384) {
        const int g = tid & 63, kc = tid >> 6;   // kc 0..5
        const int cb = g * 8;
        if (kc < 4) { WBa = hU0 + (size_t)(16 * kc) * 1024 + 2 * cb; HOa = 32 * kc; }
        else        { WBa = hV0 + (size_t)(16 * (kc - 4)) * 1024 + 2 * cb; HOa = 192 + 32 * (kc - 4); }
        STRa = 1024;                             // halfs per k-pair row
        SOa = kc * 512 + cb;
    } else if (tid < 480) {
        const int u = tid - 384;                 // 0..95
        const int kc = u >> 5;                   // 0..2
        const int g2 = u & 31;
        const int cell = g2 >> 4;
        const int cb = (g2 & 15) * 8;
        const __half* Uc = cell ? hU2 : hU1;
        const __half* Vc = cell ? hV2 : hV1;
        if (kc == 0) { WBa = Uc + 2 * cb; HOa = 128 + 32 * cell; }
        else         { WBa = Vc + (size_t)(16 * (kc - 1)) * 256 + 2 * cb; HOa = 192 + 32 * (kc - 1); }
        STRa = 256;
        SOa = 3072 + kc * 256 + cell * 128 + cb;
    }
    // ---- att1 mapping (256 active), weights in LDS (paired) ----
    int AW1o = 0, HO1 = 0, SO1 = 0;
    if (tid < 256) {
        const int g = tid & 31, kc = tid >> 5;   // kc 0..7
        const int cb = g * 8;
        AW1o = kc * 6144 + 2 * cb;               // paired: pair stride 512
        HO1 = 24 * kc;
        SO1 = kc * 256 + cb;
    }
    // ---- att2 mapping (768 active, 8 chunks x 16 pairs), paired ----
    const int kc2 = tid / 96;                    // 0..7 for tid<768
    const int g2a = tid - kc2 * 96;
    const __half* WB2 = haw2 + (size_t)(16 * kc2) * 1536 + 2 * (g2a * 8);
    const int HO2 = 32 * kc2;
    const int SO2 = kc2 * 768 + g2a * 8;
    // ---- comp1 mapping (192 active), att_out fused, paired ----
    const __half* WBc = nullptr; int HOc = 0, SOc = 0, C1o = 0, HSELo = 0, HSELm = 0, HBc = 0;
    if (tid < 128) {
        const int g = tid & 7, kc = tid >> 3;    // kc 0..15
        WBc = hcw10 + (size_t)(16 * kc) * 128 + 2 * (g * 8);
        HOc = 32 * kc;
        SOc = kc * 64 + g * 8;
        HSELo = 0; HSELm = 127; HBc = 0;
    } else if (tid < 192) {
        const int u = tid - 128;                 // 0..63
        const int cell = u >> 5;
        const int rem = u & 31;
        const int g = rem & 3, kc = rem >> 2;    // kc 0..7
        C1o = cell * 4096 + kc * 512 + 2 * (g * 8);  // paired: pair stride 64
        HOc = 512 + 128 * cell + 16 * kc;
        SOc = 1024 + cell * 256 + kc * 32 + g * 8;
        HSELo = 128 + 32 * cell; HSELm = 31; HBc = 512 + 128 * cell;
    }
    const int AHc = HOc / 192;                   // head idx (chunks never cross heads)
    // ---- gates / G-prefetch mapping (192 active) ----
    const int g12_cell = ((tid - 128) >> 5) & 1;
    const int g12_uu   = (tid - 128) & 31;

    float  g0p[4];
    __half g12p[4];
    if (tid < 128) {
        const float* gp = G0 + ((size_t)row * TT + 0) * 512;
#pragma unroll
        for (int q = 0; q < 4; ++q) g0p[q] = gp[q * 128 + tid];
    } else if (tid < 192) {
        const __half* gp = (g12_cell ? G2h : G1h) + ((size_t)row * TT + 0) * 128;
#pragma unroll
        for (int q = 0; q < 4; ++q) g12p[q] = gp[q * 32 + g12_uu];
    }

    for (int t = 0; t < TT; ++t) {
        // ======== stage A compute (L2 stream, paired dot2, rotated) ========
        if (tid < 480) {
            float acc[8];
#pragma unroll
            for (int j = 0; j < 8; ++j) acc[j] = 0.f;
#pragma unroll 8
            for (int p = 0; p < 16; ++p) {
                const int kk = (p + rotPA) & 15;
                const __half* wp = WBa + (size_t)kk * STRa;
                dot8p(acc, *(const float4*)wp, *(const float4*)(wp + 8),
                      hz[HOa + 2 * kk], hz[HOa + 2 * kk + 1]);
            }
            float* s0 = &scratch[SOa];
            *(float4*)s0       = make_float4(acc[0], acc[1], acc[2], acc[3]);
            *(float4*)(s0 + 4) = make_float4(acc[4], acc[5], acc[6], acc[7]);
        }
        BAR();
        // ======== gates ========
        if (tid < 128) {
            float s[4];
#pragma unroll
            for (int q = 0; q < 4; ++q) {
                const int c4 = q * 128 + tid;
                float v = g0p[q];
#pragma unroll
                for (int kc = 0; kc < 6; ++kc) v += scratch[kc * 512 + c4];
                s[q] = v;
            }
            const float f  = sigf(s[0]);
            const float ig = sigf(s[1]);
            const float o  = sigf(s[2]);
            const float ch = tanhf(s[3]);
            const float c = f * cst[tid] + ig * ch;
            cst[tid] = c;
            hz[tid] = tanhf(c) * o;
        } else if (tid < 192) {
            const int cell = g12_cell, uu = g12_uu;
            float s[4];
#pragma unroll
            for (int q = 0; q < 4; ++q) {
                float v = __half2float(g12p[q]);
#pragma unroll
                for (int kc = 0; kc < 3; ++kc)
                    v += scratch[3072 + kc * 256 + cell * 128 + q * 32 + uu];
                s[q] = v;
            }
            const float f  = sigf(s[0]);
            const float ig = sigf(s[1]);
            const float o  = sigf(s[2]);
            const float ch = tanhf(s[3]);
            const int si = 128 + 32 * cell + uu;
            const float c = f * cst[si] + ig * ch;
            cst[si] = c;
            hz[si] = tanhf(c) * o;
        }
        BAR();
        // ======== att1 compute (weights in LDS, paired dot2) ========
        if (tid < 256) {
            float acc[8];
#pragma unroll
            for (int j = 0; j < 8; ++j) acc[j] = 0.f;
            const __half* wp = &s_aw1[AW1o];
#pragma unroll
            for (int p = 0; p < 12; ++p)
                dot8p(acc, *(const float4*)(wp + p * 512), *(const float4*)(wp + p * 512 + 8),
                      hz[HO1 + 2 * p], hz[HO1 + 2 * p + 1]);
            float* s0 = &scratch[SO1];
            *(float4*)s0       = make_float4(acc[0], acc[1], acc[2], acc[3]);
            *(float4*)(s0 + 4) = make_float4(acc[4], acc[5], acc[6], acc[7]);
        }
        BAR();
        // ======== att1 reduce + relu ========
        if (tid < 256) {
            float s = ab1[tid];
#pragma unroll
            for (int kc = 0; kc < 8; ++kc) s += scratch[kc * 256 + tid];
            a1s[tid] = fmaxf(s, 0.f);
        }
        BAR();
        // ======== att2 compute (768 threads, 16 pairs each, rotated) ========
        if (tid < 768) {
            float acc[8];
#pragma unroll
            for (int j = 0; j < 8; ++j) acc[j] = 0.f;
#pragma unroll 8
            for (int p = 0; p < 16; ++p) {
                const int kk = (p + rotPB) & 15;
                const __half* wp = WB2 + (size_t)kk * 1536;
                dot8p(acc, *(const float4*)wp, *(const float4*)(wp + 8),
                      a1s[HO2 + 2 * kk], a1s[HO2 + 2 * kk + 1]);
            }
            float* s0 = &scratch[SO2];
            *(float4*)s0       = make_float4(acc[0], acc[1], acc[2], acc[3]);
            *(float4*)(s0 + 4) = make_float4(acc[4], acc[5], acc[6], acc[7]);
        }
        BAR();
        // ======== att2 reduce + sigmoid + exp (one pass, 768 threads) ========
        if (tid < 768) {
            float s = ab2[tid];
#pragma unroll
            for (int kc = 0; kc < 8; ++kc) s += scratch[kc * 768 + tid];
            attE[tid] = expf(sigf(s));
        }
        BAR();
        // ======== softmax reciprocal denominators ========
        if (tid < 256) {
            const int a = tid >> 6, lane = tid & 63;
            float v = attE[a * 192 + lane] + attE[a * 192 + 64 + lane]
                    + attE[a * 192 + 128 + lane];
#pragma unroll
            for (int s = 32; s >= 1; s >>= 1) v += __shfl_xor(v, s);
            if (lane == 0) rinv[a] = 1.f / v;
        }
        BAR();
        // ======== comp1 compute (att_out fused, paired dot2) ========
        if (tid < 192) {
            const float ri = rinv[AHc];
            float acc[8];
#pragma unroll
            for (int j = 0; j < 8; ++j) acc[j] = 0.f;
            if (tid < 128) {
#pragma unroll 8
                for (int p = 0; p < 16; ++p) {
                    const int kk = (p + rotPC) & 15;
                    const int i0 = HOc + 2 * kk;
                    const float a0 = attE[i0] * ri * hz[i0 & 127];
                    const float a1 = attE[i0 + 1] * ri * hz[(i0 + 1) & 127];
                    const __half* wp = WBc + (size_t)kk * 128;
                    dot8p(acc, *(const float4*)wp, *(const float4*)(wp + 8), a0, a1);
                }
            } else {
                const __half* wp = &s_c1b[C1o];
#pragma unroll
                for (int p = 0; p < 8; ++p) {
                    const int i0 = HOc + 2 * p;
                    const float a0 = attE[i0] * ri * hz[HSELo + ((i0 - HBc) & HSELm)];
                    const float a1 = attE[i0 + 1] * ri * hz[HSELo + ((i0 + 1 - HBc) & HSELm)];
                    dot8p(acc, *(const float4*)(wp + p * 64), *(const float4*)(wp + p * 64 + 8),
                          a0, a1);
                }
            }
            float* s0 = &scratch[SOc];
            *(float4*)s0       = make_float4(acc[0], acc[1], acc[2], acc[3]);
            *(float4*)(s0 + 4) = make_float4(acc[4], acc[5], acc[6], acc[7]);
        }
        BAR();
        // ======== comp1 reduce + relu ========
        if (tid < 128) {
            float s;
            if (tid < 64) {
                s = cb10[tid];
#pragma unroll
                for (int kc = 0; kc < 16; ++kc) s += scratch[kc * 64 + tid];
            } else {
                const int cc = tid - 64;
                const int cell = cc >> 5, j = cc & 31;
                s = (cell ? cb12 : cb11)[j];
#pragma unroll
                for (int kc = 0; kc < 8; ++kc)
                    s += scratch[1024 + cell * 256 + kc * 32 + j];
            }
            hid[tid] = fmaxf(s, 0.f);
        }
        BAR();
        // ======== comp2 + z softmax (one wave) ========
        if (tid < 64) {
            const int j = tid;
            float acc;
            if (j < 32) {
                acc = cb20[j];
#pragma unroll
                for (int k = 0; k < 64; ++k) acc += hid[k] * c2w[k * 32 + j];
            } else if (j < 48) {
                const int o = j - 32; acc = cb21[o];
#pragma unroll
                for (int k = 0; k < 32; ++k) acc += hid[64 + k] * c2w[2048 + k * 16 + o];
            } else {
                const int o = j - 48; acc = cb22[o];
#pragma unroll
                for (int k = 0; k < 32; ++k) acc += hid[96 + k] * c2w[2560 + k * 16 + o];
            }
            const float e = expf(sigf(acc));
            float v = e;
#pragma unroll
            for (int s = 32; s >= 1; s >>= 1) v += __shfl_xor(v, s);
            hz[192 + j] = e / v;
        }
        // ======== G prefetch for t+1 (stays in flight across BAR) ========
        {
            const int tn = (t + 1 < TT) ? t + 1 : TT - 1;
            if (tid < 128) {
                const float* gp = G0 + ((size_t)row * TT + tn) * 512;
#pragma unroll
                for (int q = 0; q < 4; ++q) g0p[q] = gp[q * 128 + tid];
            } else if (tid < 192) {
                const __half* gp = (g12_cell ? G2h : G1h) + ((size_t)row * TT + tn) * 128;
#pragma unroll
                for (int q = 0; q < 4; ++q) g12p[q] = gp[q * 32 + g12_uu];
            }
        }
        BAR();
    }

    __syncthreads();
    // ======== final MLP ========
    if (tid < 64) {
        const int j = tid;
        float acc = fb1[j];
#pragma unroll 8
        for (int k = 0; k < 64; ++k)  acc += hz[192 + k] * fw1[k * 64 + j];
#pragma unroll 8
        for (int k = 0; k < 192; ++k) acc += hz[k] * fw1[(64 + k) * 64 + j];
        hid[j] = fmaxf(acc, 0.f);
    }
    __syncthreads();
    if (tid < 64) {
        float v = hid[tid] * fw2[tid];
#pragma unroll
        for (int s = 32; s >= 1; s >>= 1) v += __shfl_xor(v, s);
        if (tid == 0) out[row] = v + fb2[0];
    }
}

// ---------------------------------------------------------------------------
extern "C" void kernel_launch(void* const* d_in, const int* in_sizes, int n_in,
                              void* d_out, int out_size, void* d_ws, size_t ws_size,
                              hipStream_t stream) {
    const float* x0   = (const float*)d_in[0];
    const float* x1   = (const float*)d_in[1];
    const float* x2   = (const float*)d_in[2];
    const float* W0   = (const float*)d_in[3];
    const float* U0   = (const float*)d_in[4];
    const float* V0   = (const float*)d_in[5];
    const float* b0   = (const float*)d_in[6];
    const float* W1   = (const float*)d_in[7];
    const float* U1   = (const float*)d_in[8];
    const float* V1   = (const float*)d_in[9];
    const float* b1   = (const float*)d_in[10];
    const float* W2   = (const float*)d_in[11];
    const float* U2   = (const float*)d_in[12];
    const float* V2   = (const float*)d_in[13];
    const float* b2   = (const float*)d_in[14];
    const float* aw1  = (const float*)d_in[15];
    const float* ab1  = (const float*)d_in[16];
    const float* aw2  = (const float*)d_in[17];
    const float* ab2  = (const float*)d_in[18];
    const float* cw10 = (const float*)d_in[19];
    const float* cb10 = (const float*)d_in[20];
    const float* cw20 = (const float*)d_in[21];
    const float* cb20 = (const float*)d_in[22];
    const float* cw11 = (const float*)d_in[23];
    const float* cb11 = (const float*)d_in[24];
    const float* cw21 = (const float*)d_in[25];
    const float* cb21 = (const float*)d_in[26];
    const float* cw12 = (const float*)d_in[27];
    const float* cb12 = (const float*)d_in[28];
    const float* cw22 = (const float*)d_in[29];
    const float* cb22 = (const float*)d_in[30];
    const float* fw1  = (const float*)d_in[31];
    const float* fb1  = (const float*)d_in[32];
    const float* fw2  = (const float*)d_in[33];
    const float* fb2  = (const float*)d_in[34];
    float* out = (float*)d_out;

    const size_t M = (size_t)BB * TT;   // 65536

    float*  G0  = (float*)d_ws;                 // M*512 f32
    __half* G1h = (__half*)(G0 + M * 512);      // M*128 f16
    __half* G2h = G1h + M * 128;                // M*128 f16
    __half* hU0   = G2h + M * 128;              // paired layouts below
    __half* hV0   = hU0 + 65536;
    __half* hU1   = hV0 + 32768;
    __half* hV1   = hU1 + 4096;
    __half* hU2   = hV1 + 8192;
    __half* hV2   = hU2 + 4096;
    __half* haw1  = hV2 + 8192;
    __half* haw2  = haw1 + 49152;
    __half* hcw10 = haw2 + 196608;
    __half* hcw11 = hcw10 + 32768;
    __half* hcw12 = hcw11 + 4096;

    f2h_pair<<<(65536 + 255) / 256, 256, 0, stream>>>(U0, hU0, 128, 512);
    f2h_pair<<<(32768 + 255) / 256, 256, 0, stream>>>(V0, hV0, 64, 512);
    f2h_pair<<<(4096 + 255) / 256, 256, 0, stream>>>(U1, hU1, 32, 128);
    f2h_pair<<<(8192 + 255) / 256, 256, 0, stream>>>(V1, hV1, 64, 128);
    f2h_pair<<<(4096 + 255) / 256, 256, 0, stream>>>(U2, hU2, 32, 128);
    f2h_pair<<<(8192 + 255) / 256, 256, 0, stream>>>(V2, hV2, 64, 128);
    f2h_pair<<<(49152 + 255) / 256, 256, 0, stream>>>(aw1, haw1, 192, 256);
    f2h_pair<<<(196608 + 255) / 256, 256, 0, stream>>>(aw2, haw2, 256, 768);
    f2h_pair<<<(32768 + 255) / 256, 256, 0, stream>>>(cw10, hcw10, 512, 64);
    f2h_pair<<<(4096 + 255) / 256, 256, 0, stream>>>(cw11, hcw11, 128, 32);
    f2h_pair<<<(4096 + 255) / 256, 256, 0, stream>>>(cw12, hcw12, 128, 32);

    xw_gemm<float><<<dim3(512 / GT_N, M / GT_M), 256, 0, stream>>>(x0, W0, b0, G0, (int)M, 512, 300);
    xw_gemm<__half><<<dim3(128 / GT_N, M / GT_M), 256, 0, stream>>>(x1, W1, b1, G1h, (int)M, 128, 74);
    xw_gemm<__half><<<dim3(128 / GT_N, M / GT_M), 256, 0, stream>>>(x2, W2, b2, G2h, (int)M, 128, 35);

    // 256 blocks x 1024 threads, 1 row/block
    marn_rec<<<256, 1024, 0, stream>>>(G0, G1h, G2h, hU0, hV0, hU1, hV1, hU2, hV2,
                                       haw1, ab1, haw2, ab2,
                                       hcw10, cb10, cw20, cb20,
                                       hcw11, cb11, cw21, cb21,
                                       hcw12, cb12, cw22, cb22,
                                       fw1, fb1, fw2, fb2, out);
}

// Round 10
// 3856.667 us; speedup vs baseline: 1.0227x; 1.0227x over previous
//
#include <hip/hip_runtime.h>
#include <hip/hip_bf16.h>
#include <hip/hip_fp16.h>
#include <math.h>

#define BB 256
#define TT 256
// H=[128,32,32], TH=192, ZDIM=64, ATT=4

__device__ __forceinline__ float sigf(float x) { return 1.f / (1.f + expf(-x)); }

typedef _Float16 half8v __attribute__((ext_vector_type(8)));
typedef _Float16 half2v __attribute__((ext_vector_type(2)));

// Paired dot: weights in [k/2][2N] interleave — wv0/wv1 = 8 outputs x k-pair.
__device__ __forceinline__ void dot8p(float (&acc)[8], float4 wv0, float4 wv1,
                                      float a0, float a1) {
#if __has_builtin(__builtin_amdgcn_fdot2)
    const half2v ap = __builtin_bit_cast(half2v, __builtin_amdgcn_cvt_pkrtz(a0, a1));
    acc[0] = __builtin_amdgcn_fdot2(__builtin_bit_cast(half2v, wv0.x), ap, acc[0], false);
    acc[1] = __builtin_amdgcn_fdot2(__builtin_bit_cast(half2v, wv0.y), ap, acc[1], false);
    acc[2] = __builtin_amdgcn_fdot2(__builtin_bit_cast(half2v, wv0.z), ap, acc[2], false);
    acc[3] = __builtin_amdgcn_fdot2(__builtin_bit_cast(half2v, wv0.w), ap, acc[3], false);
    acc[4] = __builtin_amdgcn_fdot2(__builtin_bit_cast(half2v, wv1.x), ap, acc[4], false);
    acc[5] = __builtin_amdgcn_fdot2(__builtin_bit_cast(half2v, wv1.y), ap, acc[5], false);
    acc[6] = __builtin_amdgcn_fdot2(__builtin_bit_cast(half2v, wv1.z), ap, acc[6], false);
    acc[7] = __builtin_amdgcn_fdot2(__builtin_bit_cast(half2v, wv1.w), ap, acc[7], false);
#else
    half8v h0 = __builtin_bit_cast(half8v, wv0);
    half8v h1 = __builtin_bit_cast(half8v, wv1);
#pragma unroll
    for (int m = 0; m < 4; ++m) acc[m]     += (float)h0[2*m] * a0 + (float)h0[2*m+1] * a1;
#pragma unroll
    for (int m = 0; m < 4; ++m) acc[4 + m] += (float)h1[2*m] * a0 + (float)h1[2*m+1] * a1;
#endif
}

// lgkm-only barrier: drains LDS ops; global loads stay in flight across it.
#define BAR() do {                                   \
    __atomic_signal_fence(__ATOMIC_SEQ_CST);         \
    __builtin_amdgcn_s_waitcnt(0xC07F);              \
    __builtin_amdgcn_s_barrier();                    \
    __atomic_signal_fence(__ATOMIC_SEQ_CST);         \
} while (0)

// f32 [K][N] -> f16 paired layout: (k,j) -> (k>>1)*2N + 2j + (k&1).
__global__ void f2h_pair(const float* __restrict__ s, __half* __restrict__ d,
                         int K, int N) {
    int i = blockIdx.x * 256 + threadIdx.x;
    if (i < K * N) {
        int k = i / N, j = i - k * N;
        d[(size_t)(k >> 1) * (2 * N) + 2 * j + (k & 1)] = __float2half(s[i]);
    }
}

// ---------------------------------------------------------------------------
// Kernel 1: G = X @ W + bias
// ---------------------------------------------------------------------------
#define GT_M 128
#define GT_N 64
#define GT_K 16

__device__ __forceinline__ void stvec4(float* p, float4 v) { *(float4*)p = v; }
__device__ __forceinline__ void stvec4(__half* p, float4 v) {
    *(__half2*)p = __floats2half2_rn(v.x, v.y);
    *(__half2*)(p + 2) = __floats2half2_rn(v.z, v.w);
}

template <typename OT>
__global__ __launch_bounds__(256)
void xw_gemm(const float* __restrict__ X, const float* __restrict__ W,
             const float* __restrict__ bias, OT* __restrict__ G,
             int M, int N, int K) {
    __shared__ float As[GT_K][GT_M + 4];
    __shared__ float Bs[GT_K][GT_N];
    const int tid = threadIdx.x;
    const int bm = blockIdx.y * GT_M;
    const int bn = blockIdx.x * GT_N;
    const int tx = tid & 15;
    const int ty = tid >> 4;

    float acc[8][4];
#pragma unroll
    for (int i = 0; i < 8; ++i)
#pragma unroll
        for (int j = 0; j < 4; ++j) acc[i][j] = 0.f;

    for (int kt = 0; kt < K; kt += GT_K) {
#pragma unroll
        for (int i = 0; i < 8; ++i) {
            int idx = i * 256 + tid;
            int m = idx >> 4, k = idx & 15;
            int gk = kt + k;
            As[k][m] = (gk < K) ? X[(size_t)(bm + m) * K + gk] : 0.f;
        }
#pragma unroll
        for (int i = 0; i < 4; ++i) {
            int idx = i * 256 + tid;
            int k = idx >> 6, n = idx & 63;
            int gk = kt + k;
            Bs[k][n] = (gk < K) ? W[(size_t)gk * N + bn + n] : 0.f;
        }
        __syncthreads();
#pragma unroll
        for (int k = 0; k < GT_K; ++k) {
            float a[8], b[4];
            const float4 a0 = *(const float4*)&As[k][ty * 8];
            const float4 a1 = *(const float4*)&As[k][ty * 8 + 4];
            const float4 bv = *(const float4*)&Bs[k][tx * 4];
            a[0]=a0.x; a[1]=a0.y; a[2]=a0.z; a[3]=a0.w;
            a[4]=a1.x; a[5]=a1.y; a[6]=a1.z; a[7]=a1.w;
            b[0]=bv.x; b[1]=bv.y; b[2]=bv.z; b[3]=bv.w;
#pragma unroll
            for (int i = 0; i < 8; ++i)
#pragma unroll
                for (int j = 0; j < 4; ++j) acc[i][j] += a[i] * b[j];
        }
        __syncthreads();
    }
    const int n0 = bn + tx * 4;
#pragma unroll
    for (int i = 0; i < 8; ++i) {
        int m = bm + ty * 8 + i;
        float4 v;
        v.x = acc[i][0] + bias[n0 + 0];
        v.y = acc[i][1] + bias[n0 + 1];
        v.z = acc[i][2] + bias[n0 + 2];
        v.w = acc[i][3] + bias[n0 + 3];
        stvec4(&G[(size_t)m * N + n0], v);
    }
}

// ---------------------------------------------------------------------------
// Kernel 2: persistent recurrence. 128 blocks x 512 threads, 2 ROWS/block.
// r10: row-pairing — each weight float4 loaded once serves both rows' fdot2
// (per-row stream bytes halved; VALU/CU doubles but overlaps on the VALU
// pipe). L2-streamed phases (stageA/att2/cw10) compute both rows per thread
// (acc0+acc1, +8 VGPR); LDS phases (att1/gates/reduces/comp2) thread-split:
// tid>=256 => row1, so per-thread state stays one-row (no VGPR growth).
// s_c1b evicted from LDS (cw11/12 streamed) to fit doubled state (~150KB).
// VGPR hard-cap 128 (r1/r2/r4/r9). r5 k-rotation. r6/7 fdot2 paired layout.
// ---------------------------------------------------------------------------
__global__ __launch_bounds__(512, 1)
void marn_rec(const float* __restrict__ G0, const __half* __restrict__ G1h,
              const __half* __restrict__ G2h,
              const __half* __restrict__ hU0, const __half* __restrict__ hV0,
              const __half* __restrict__ hU1, const __half* __restrict__ hV1,
              const __half* __restrict__ hU2, const __half* __restrict__ hV2,
              const __half* __restrict__ haw1, const float* __restrict__ ab1,
              const __half* __restrict__ haw2, const float* __restrict__ ab2,
              const __half* __restrict__ hcw10, const float* __restrict__ cb10,
              const float* __restrict__ cw20, const float* __restrict__ cb20,
              const __half* __restrict__ hcw11, const float* __restrict__ cb11,
              const float* __restrict__ cw21, const float* __restrict__ cb21,
              const __half* __restrict__ hcw12, const float* __restrict__ cb12,
              const float* __restrict__ cw22, const float* __restrict__ cb22,
              const float* __restrict__ fw1, const float* __restrict__ fb1,
              const float* __restrict__ fw2, const float* __restrict__ fb2,
              float* __restrict__ out) {
    __shared__ float hz[512];     // per row 256: [h0|h1|h2|z]; row1 at +256
    __shared__ float cst[384];    // row1 at +192
    __shared__ float a1s[512];    // row1 at +256
    __shared__ float attE[1536];  // row1 at +768
    __shared__ float hid[256];    // row1 at +128
    __shared__ float rinv[8];     // row1 at +4
    __shared__ float scratch[7680];  // row1 at +3840
    __shared__ float c2w[3072];   // cw20(2048)|cw21(512)|cw22(512)
    __shared__ __align__(16) __half s_aw1[49152];  // att1 weights, paired, pinned

    const int tid = threadIdx.x;
    const int bid = blockIdx.x;
    const int row0 = 2 * bid;
    // de-contention rotation offsets, in k-PAIRS (r5 mechanism)
    const int rotPA = ((bid >> 3) & 3) * 4;
    const int rotPB = ((bid >> 3) & 7) * 4;
    const int rotPC = ((bid >> 3) & 3) * 4;

    hz[tid] = 0.f;
    if (tid < 384) cst[tid] = 0.f;
    for (int i = tid; i < 2048; i += 512) c2w[i] = cw20[i];
    { c2w[2048 + tid] = cw21[tid & 511]; c2w[2560 + tid] = cw22[tid & 511]; }
    {
        const float4* s4 = (const float4*)haw1;
        float4* d4 = (float4*)s_aw1;
        for (int i = tid; i < 6144; i += 512) d4[i] = s4[i];
    }
    __syncthreads();

    // ---- stage A mapping (480 active), paired layout ----
    const __half* WBa = nullptr; int HOa = 0, STRa = 0, SOa = 0;
    if (tid < 384) {
        const int g = tid & 63, kc = tid >> 6;   // kc 0..5
        const int cb = g * 8;
        if (kc < 4) { WBa = hU0 + (size_t)(16 * kc) * 1024 + 2 * cb; HOa = 32 * kc; }
        else        { WBa = hV0 + (size_t)(16 * (kc - 4)) * 1024 + 2 * cb; HOa = 192 + 32 * (kc - 4); }
        STRa = 1024;
        SOa = kc * 512 + cb;
    } else if (tid < 480) {
        const int u = tid - 384;
        const int kc = u >> 5;
        const int g2 = u & 31;
        const int cell = g2 >> 4;
        const int cb = (g2 & 15) * 8;
        const __half* Uc = cell ? hU2 : hU1;
        const __half* Vc = cell ? hV2 : hV1;
        if (kc == 0) { WBa = Uc + 2 * cb; HOa = 128 + 32 * cell; }
        else         { WBa = Vc + (size_t)(16 * (kc - 1)) * 256 + 2 * cb; HOa = 192 + 32 * (kc - 1); }
        STRa = 256;
        SOa = 3072 + kc * 256 + cell * 128 + cb;
    }
    // ---- att1 mapping (all 512: tid>=256 is row1 twin) ----
    const int lt = tid & 255;
    const int rr = tid >> 8;                     // row select (0/1)
    int AW1o, HO1, SO1;
    {
        const int g = lt & 31, kc = lt >> 5;
        AW1o = kc * 6144 + 2 * (g * 8);
        HO1 = 24 * kc;
        SO1 = kc * 256 + g * 8;
    }
    // ---- att2 mapping (384 active, 4 chunks x 32 pairs), paired ----
    const int kc2 = tid / 96;
    const int g2a = tid - kc2 * 96;
    const __half* WB2 = haw2 + (size_t)(32 * kc2) * 1536 + 2 * (g2a * 8);
    const int HO2 = 64 * kc2;
    const int SO2 = kc2 * 768 + g2a * 8;
    // ---- comp1 mapping: tid<128 cw10 (both rows); tid 128..255 small
    //      (tid-128)>>6 selects row, u=(tid-128)&63 as r7's small mapping ----
    const __half* WBc = nullptr; const __half* WC1 = nullptr;
    int HOc = 0, SOc = 0, HSELo = 0, HSELm = 0, HBc = 0, AHc = 0, c1row = 0;
    if (tid < 128) {
        const int g = tid & 7, kc = tid >> 3;
        WBc = hcw10 + (size_t)(16 * kc) * 128 + 2 * (g * 8);
        HOc = 32 * kc;
        SOc = kc * 64 + g * 8;
        AHc = HOc / 192;
    } else if (tid < 256) {
        const int u = (tid - 128) & 63;
        c1row = (tid - 128) >> 6;
        const int cell = u >> 5;
        const int rem = u & 31;
        const int g = rem & 3, kc = rem >> 2;
        WC1 = (cell ? hcw12 : hcw11) + kc * 512 + 2 * (g * 8);
        HOc = 512 + 128 * cell + 16 * kc;
        SOc = 1024 + cell * 256 + kc * 32 + g * 8;
        HSELo = 128 + 32 * cell; HSELm = 31; HBc = 512 + 128 * cell;
        AHc = HOc / 192;
    }
    // ---- gates / G-prefetch thread roles ----
    const bool gBig   = (tid < 128) || (tid >= 256 && tid < 384);   // cell0 of its row
    const bool gSmall = (lt >= 128 && lt < 192);                    // small cells of its row
    const int  gC     = tid & 127;               // col for gBig
    const int  sCell  = ((lt - 128) >> 5) & 1;   // for gSmall
    const int  sUU    = (lt - 128) & 31;

    float  g0p[4];
    __half g12p[4];
    if (gBig) {
        const float* gp = G0 + ((size_t)(row0 + rr) * TT + 0) * 512;
#pragma unroll
        for (int q = 0; q < 4; ++q) g0p[q] = gp[q * 128 + gC];
    } else if (gSmall) {
        const __half* gp = (sCell ? G2h : G1h) + ((size_t)(row0 + rr) * TT + 0) * 128;
#pragma unroll
        for (int q = 0; q < 4; ++q) g12p[q] = gp[q * 32 + sUU];
    }

    for (int t = 0; t < TT; ++t) {
        // ======== stage A: both rows per thread (shared weight loads) ========
        if (tid < 480) {
            float acc0[8], acc1[8];
#pragma unroll
            for (int j = 0; j < 8; ++j) { acc0[j] = 0.f; acc1[j] = 0.f; }
#pragma unroll 8
            for (int p = 0; p < 16; ++p) {
                const int kk = (p + rotPA) & 15;
                const __half* wp = WBa + (size_t)kk * STRa;
                const float4 wv0 = *(const float4*)wp;
                const float4 wv1 = *(const float4*)(wp + 8);
                dot8p(acc0, wv0, wv1, hz[HOa + 2 * kk], hz[HOa + 2 * kk + 1]);
                dot8p(acc1, wv0, wv1, hz[256 + HOa + 2 * kk], hz[256 + HOa + 2 * kk + 1]);
            }
            float* s0 = &scratch[SOa];
            *(float4*)s0       = make_float4(acc0[0], acc0[1], acc0[2], acc0[3]);
            *(float4*)(s0 + 4) = make_float4(acc0[4], acc0[5], acc0[6], acc0[7]);
            float* s1 = &scratch[3840 + SOa];
            *(float4*)s1       = make_float4(acc1[0], acc1[1], acc1[2], acc1[3]);
            *(float4*)(s1 + 4) = make_float4(acc1[4], acc1[5], acc1[6], acc1[7]);
        }
        BAR();
        // ======== gates (each thread: its row) ========
        if (gBig) {
            const float* scr = scratch + rr * 3840;
            float s[4];
#pragma unroll
            for (int q = 0; q < 4; ++q) {
                const int c4 = q * 128 + gC;
                float v = g0p[q];
#pragma unroll
                for (int kc = 0; kc < 6; ++kc) v += scr[kc * 512 + c4];
                s[q] = v;
            }
            const float f  = sigf(s[0]);
            const float ig = sigf(s[1]);
            const float o  = sigf(s[2]);
            const float ch = tanhf(s[3]);
            const int ci = rr * 192 + gC;
            const float c = f * cst[ci] + ig * ch;
            cst[ci] = c;
            hz[rr * 256 + gC] = tanhf(c) * o;
        } else if (gSmall) {
            const float* scr = scratch + rr * 3840;
            float s[4];
#pragma unroll
            for (int q = 0; q < 4; ++q) {
                float v = __half2float(g12p[q]);
#pragma unroll
                for (int kc = 0; kc < 3; ++kc)
                    v += scr[3072 + kc * 256 + sCell * 128 + q * 32 + sUU];
                s[q] = v;
            }
            const float f  = sigf(s[0]);
            const float ig = sigf(s[1]);
            const float o  = sigf(s[2]);
            const float ch = tanhf(s[3]);
            const int si = 128 + 32 * sCell + sUU;
            const float c = f * cst[rr * 192 + si] + ig * ch;
            cst[rr * 192 + si] = c;
            hz[rr * 256 + si] = tanhf(c) * o;
        }
        BAR();
        // ======== att1: 512 threads, tid>=256 = row1 (weights LDS) ========
        {
            const float* hzB = hz + rr * 256;
            float acc[8];
#pragma unroll
            for (int j = 0; j < 8; ++j) acc[j] = 0.f;
            const __half* wp = &s_aw1[AW1o];
#pragma unroll
            for (int p = 0; p < 12; ++p)
                dot8p(acc, *(const float4*)(wp + p * 512), *(const float4*)(wp + p * 512 + 8),
                      hzB[HO1 + 2 * p], hzB[HO1 + 2 * p + 1]);
            float* s0 = &scratch[rr * 3840 + SO1];
            *(float4*)s0       = make_float4(acc[0], acc[1], acc[2], acc[3]);
            *(float4*)(s0 + 4) = make_float4(acc[4], acc[5], acc[6], acc[7]);
        }
        BAR();
        // ======== att1 reduce + relu (512 threads, row-split) ========
        {
            const float* scr = scratch + rr * 3840;
            float s = ab1[lt];
#pragma unroll
            for (int kc = 0; kc < 8; ++kc) s += scr[kc * 256 + lt];
            a1s[rr * 256 + lt] = fmaxf(s, 0.f);
        }
        BAR();
        // ======== att2: both rows per thread (shared weight loads) ========
        if (tid < 384) {
            float acc0[8], acc1[8];
#pragma unroll
            for (int j = 0; j < 8; ++j) { acc0[j] = 0.f; acc1[j] = 0.f; }
#pragma unroll 8
            for (int p = 0; p < 32; ++p) {
                const int kk = (p + rotPB) & 31;
                const __half* wp = WB2 + (size_t)kk * 1536;
                const float4 wv0 = *(const float4*)wp;
                const float4 wv1 = *(const float4*)(wp + 8);
                dot8p(acc0, wv0, wv1, a1s[HO2 + 2 * kk], a1s[HO2 + 2 * kk + 1]);
                dot8p(acc1, wv0, wv1, a1s[256 + HO2 + 2 * kk], a1s[256 + HO2 + 2 * kk + 1]);
            }
            float* s0 = &scratch[SO2];
            *(float4*)s0       = make_float4(acc0[0], acc0[1], acc0[2], acc0[3]);
            *(float4*)(s0 + 4) = make_float4(acc0[4], acc0[5], acc0[6], acc0[7]);
            float* s1 = &scratch[3840 + SO2];
            *(float4*)s1       = make_float4(acc1[0], acc1[1], acc1[2], acc1[3]);
            *(float4*)(s1 + 4) = make_float4(acc1[4], acc1[5], acc1[6], acc1[7]);
        }
        BAR();
        // ======== att2 reduce + sigmoid + exp (both rows) ========
#pragma unroll
        for (int i = 0; i < 2; ++i) {
            const int idx = i * 512 + tid;
            if (idx < 768) {
                float s = ab2[idx];
#pragma unroll
                for (int kc = 0; kc < 4; ++kc) s += scratch[kc * 768 + idx];
                attE[idx] = expf(sigf(s));
            }
        }
#pragma unroll
        for (int i = 0; i < 2; ++i) {
            const int idx = i * 512 + tid;
            if (idx < 768) {
                float s = ab2[idx];
#pragma unroll
                for (int kc = 0; kc < 4; ++kc) s += scratch[3840 + kc * 768 + idx];
                attE[768 + idx] = expf(sigf(s));
            }
        }
        BAR();
        // ======== softmax reciprocal denominators (row-split) ========
        {
            const int a = lt >> 6, lane = lt & 63;
            const float* aE = attE + rr * 768;
            float v = aE[a * 192 + lane] + aE[a * 192 + 64 + lane]
                    + aE[a * 192 + 128 + lane];
#pragma unroll
            for (int s = 32; s >= 1; s >>= 1) v += __shfl_xor(v, s);
            if (lane == 0) rinv[rr * 4 + a] = 1.f / v;
        }
        BAR();
        // ======== comp1: cw10 both rows (tid<128); small row-split ========
        if (tid < 128) {
            const float ri0 = rinv[AHc], ri1 = rinv[4 + AHc];
            float acc0[8], acc1[8];
#pragma unroll
            for (int j = 0; j < 8; ++j) { acc0[j] = 0.f; acc1[j] = 0.f; }
#pragma unroll 8
            for (int p = 0; p < 16; ++p) {
                const int kk = (p + rotPC) & 15;
                const int i0 = HOc + 2 * kk;
                const float a00 = attE[i0] * ri0 * hz[i0 & 127];
                const float a01 = attE[i0 + 1] * ri0 * hz[(i0 + 1) & 127];
                const float a10 = attE[768 + i0] * ri1 * hz[256 + (i0 & 127)];
                const float a11 = attE[768 + i0 + 1] * ri1 * hz[256 + ((i0 + 1) & 127)];
                const __half* wp = WBc + (size_t)kk * 128;
                const float4 wv0 = *(const float4*)wp;
                const float4 wv1 = *(const float4*)(wp + 8);
                dot8p(acc0, wv0, wv1, a00, a01);
                dot8p(acc1, wv0, wv1, a10, a11);
            }
            float* s0 = &scratch[SOc];
            *(float4*)s0       = make_float4(acc0[0], acc0[1], acc0[2], acc0[3]);
            *(float4*)(s0 + 4) = make_float4(acc0[4], acc0[5], acc0[6], acc0[7]);
            float* s1 = &scratch[3840 + SOc];
            *(float4*)s1       = make_float4(acc1[0], acc1[1], acc1[2], acc1[3]);
            *(float4*)(s1 + 4) = make_float4(acc1[4], acc1[5], acc1[6], acc1[7]);
        } else if (tid < 256) {
            const float ri = rinv[c1row * 4 + AHc];
            const float* aE = attE + c1row * 768;
            const float* hzB = hz + c1row * 256;
            float acc[8];
#pragma unroll
            for (int j = 0; j < 8; ++j) acc[j] = 0.f;
#pragma unroll
            for (int p = 0; p < 8; ++p) {
                const int i0 = HOc + 2 * p;
                const float a0 = aE[i0] * ri * hzB[HSELo + ((i0 - HBc) & HSELm)];
                const float a1 = aE[i0 + 1] * ri * hzB[HSELo + ((i0 + 1 - HBc) & HSELm)];
                const __half* wp = WC1 + p * 64;
                dot8p(acc, *(const float4*)wp, *(const float4*)(wp + 8), a0, a1);
            }
            float* s0 = &scratch[c1row * 3840 + SOc];
            *(float4*)s0       = make_float4(acc[0], acc[1], acc[2], acc[3]);
            *(float4*)(s0 + 4) = make_float4(acc[4], acc[5], acc[6], acc[7]);
        }
        BAR();
        // ======== comp1 reduce + relu (row-split) ========
        if (gBig) {
            const float* scr = scratch + rr * 3840;
            float s;
            if (gC < 64) {
                s = cb10[gC];
#pragma unroll
                for (int kc = 0; kc < 16; ++kc) s += scr[kc * 64 + gC];
            } else {
                const int cc = gC - 64;
                const int cell = cc >> 5, j = cc & 31;
                s = (cell ? cb12 : cb11)[j];
#pragma unroll
                for (int kc = 0; kc < 8; ++kc)
                    s += scr[1024 + cell * 256 + kc * 32 + j];
            }
            hid[rr * 128 + gC] = fmaxf(s, 0.f);
        }
        BAR();
        // ======== comp2 + z softmax (one wave per row) ========
        if (tid < 64 || (tid >= 256 && tid < 320)) {
            const int j = tid & 63;
            const float* hb = hid + rr * 128;
            float acc;
            if (j < 32) {
                acc = cb20[j];
#pragma unroll
                for (int k = 0; k < 64; ++k) acc += hb[k] * c2w[k * 32 + j];
            } else if (j < 48) {
                const int o = j - 32; acc = cb21[o];
#pragma unroll
                for (int k = 0; k < 32; ++k) acc += hb[64 + k] * c2w[2048 + k * 16 + o];
            } else {
                const int o = j - 48; acc = cb22[o];
#pragma unroll
                for (int k = 0; k < 32; ++k) acc += hb[96 + k] * c2w[2560 + k * 16 + o];
            }
            const float e = expf(sigf(acc));
            float v = e;
#pragma unroll
            for (int s = 32; s >= 1; s >>= 1) v += __shfl_xor(v, s);
            hz[rr * 256 + 192 + j] = e / v;
        }
        // ======== G prefetch for t+1 (stays in flight across BAR) ========
        {
            const int tn = (t + 1 < TT) ? t + 1 : TT - 1;
            if (gBig) {
                const float* gp = G0 + ((size_t)(row0 + rr) * TT + tn) * 512;
#pragma unroll
                for (int q = 0; q < 4; ++q) g0p[q] = gp[q * 128 + gC];
            } else if (gSmall) {
                const __half* gp = (sCell ? G2h : G1h) + ((size_t)(row0 + rr) * TT + tn) * 128;
#pragma unroll
                for (int q = 0; q < 4; ++q) g12p[q] = gp[q * 32 + sUU];
            }
        }
        BAR();
    }

    __syncthreads();
    // ======== final MLP (one wave per row) ========
    if (tid < 64 || (tid >= 256 && tid < 320)) {
        const int j = tid & 63;
        const float* hzB = hz + rr * 256;
        float acc = fb1[j];
#pragma unroll 8
        for (int k = 0; k < 64; ++k)  acc += hzB[192 + k] * fw1[k * 64 + j];
#pragma unroll 8
        for (int k = 0; k < 192; ++k) acc += hzB[k] * fw1[(64 + k) * 64 + j];
        hid[rr * 128 + j] = fmaxf(acc, 0.f);
    }
    __syncthreads();
    if (tid < 64 || (tid >= 256 && tid < 320)) {
        const int j = tid & 63;
        float v = hid[rr * 128 + j] * fw2[j];
#pragma unroll
        for (int s = 32; s >= 1; s >>= 1) v += __shfl_xor(v, s);
        if (j == 0) out[row0 + rr] = v + fb2[0];
    }
}

// ---------------------------------------------------------------------------
extern "C" void kernel_launch(void* const* d_in, const int* in_sizes, int n_in,
                              void* d_out, int out_size, void* d_ws, size_t ws_size,
                              hipStream_t stream) {
    const float* x0   = (const float*)d_in[0];
    const float* x1   = (const float*)d_in[1];
    const float* x2   = (const float*)d_in[2];
    const float* W0   = (const float*)d_in[3];
    const float* U0   = (const float*)d_in[4];
    const float* V0   = (const float*)d_in[5];
    const float* b0   = (const float*)d_in[6];
    const float* W1   = (const float*)d_in[7];
    const float* U1   = (const float*)d_in[8];
    const float* V1   = (const float*)d_in[9];
    const float* b1   = (const float*)d_in[10];
    const float* W2   = (const float*)d_in[11];
    const float* U2   = (const float*)d_in[12];
    const float* V2   = (const float*)d_in[13];
    const float* b2   = (const float*)d_in[14];
    const float* aw1  = (const float*)d_in[15];
    const float* ab1  = (const float*)d_in[16];
    const float* aw2  = (const float*)d_in[17];
    const float* ab2  = (const float*)d_in[18];
    const float* cw10 = (const float*)d_in[19];
    const float* cb10 = (const float*)d_in[20];
    const float* cw20 = (const float*)d_in[21];
    const float* cb20 = (const float*)d_in[22];
    const float* cw11 = (const float*)d_in[23];
    const float* cb11 = (const float*)d_in[24];
    const float* cw21 = (const float*)d_in[25];
    const float* cb21 = (const float*)d_in[26];
    const float* cw12 = (const float*)d_in[27];
    const float* cb12 = (const float*)d_in[28];
    const float* cw22 = (const float*)d_in[29];
    const float* cb22 = (const float*)d_in[30];
    const float* fw1  = (const float*)d_in[31];
    const float* fb1  = (const float*)d_in[32];
    const float* fw2  = (const float*)d_in[33];
    const float* fb2  = (const float*)d_in[34];
    float* out = (float*)d_out;

    const size_t M = (size_t)BB * TT;   // 65536

    float*  G0  = (float*)d_ws;                 // M*512 f32
    __half* G1h = (__half*)(G0 + M * 512);      // M*128 f16
    __half* G2h = G1h + M * 128;                // M*128 f16
    __half* hU0   = G2h + M * 128;              // paired layouts below
    __half* hV0   = hU0 + 65536;
    __half* hU1   = hV0 + 32768;
    __half* hV1   = hU1 + 4096;
    __half* hU2   = hV1 + 8192;
    __half* hV2   = hU2 + 4096;
    __half* haw1  = hV2 + 8192;
    __half* haw2  = haw1 + 49152;
    __half* hcw10 = haw2 + 196608;
    __half* hcw11 = hcw10 + 32768;
    __half* hcw12 = hcw11 + 4096;

    f2h_pair<<<(65536 + 255) / 256, 256, 0, stream>>>(U0, hU0, 128, 512);
    f2h_pair<<<(32768 + 255) / 256, 256, 0, stream>>>(V0, hV0, 64, 512);
    f2h_pair<<<(4096 + 255) / 256, 256, 0, stream>>>(U1, hU1, 32, 128);
    f2h_pair<<<(8192 + 255) / 256, 256, 0, stream>>>(V1, hV1, 64, 128);
    f2h_pair<<<(4096 + 255) / 256, 256, 0, stream>>>(U2, hU2, 32, 128);
    f2h_pair<<<(8192 + 255) / 256, 256, 0, stream>>>(V2, hV2, 64, 128);
    f2h_pair<<<(49152 + 255) / 256, 256, 0, stream>>>(aw1, haw1, 192, 256);
    f2h_pair<<<(196608 + 255) / 256, 256, 0, stream>>>(aw2, haw2, 256, 768);
    f2h_pair<<<(32768 + 255) / 256, 256, 0, stream>>>(cw10, hcw10, 512, 64);
    f2h_pair<<<(4096 + 255) / 256, 256, 0, stream>>>(cw11, hcw11, 128, 32);
    f2h_pair<<<(4096 + 255) / 256, 256, 0, stream>>>(cw12, hcw12, 128, 32);

    xw_gemm<float><<<dim3(512 / GT_N, M / GT_M), 256, 0, stream>>>(x0, W0, b0, G0, (int)M, 512, 300);
    xw_gemm<__half><<<dim3(128 / GT_N, M / GT_M), 256, 0, stream>>>(x1, W1, b1, G1h, (int)M, 128, 74);
    xw_gemm<__half><<<dim3(128 / GT_N, M / GT_M), 256, 0, stream>>>(x2, W2, b2, G2h, (int)M, 128, 35);

    // 128 blocks x 512 threads, 2 rows/block
    marn_rec<<<128, 512, 0, stream>>>(G0, G1h, G2h, hU0, hV0, hU1, hV1, hU2, hV2,
                                      haw1, ab1, haw2, ab2,
                                      hcw10, cb10, cw20, cb20,
                                      hcw11, cb11, cw21, cb21,
                                      hcw12, cb12, cw22, cb22,
                                      fw1, fb1, fw2, fb2, out);
}

// Round 11
// 3199.799 us; speedup vs baseline: 1.2326x; 1.2053x over previous
//
#include <hip/hip_runtime.h>
#include <hip/hip_bf16.h>
#include <hip/hip_fp16.h>
#include <math.h>

#define BB 256
#define TT 256
// H=[128,32,32], TH=192, ZDIM=64, ATT=4

__device__ __forceinline__ float sigf(float x) { return 1.f / (1.f + expf(-x)); }

typedef _Float16 half8v __attribute__((ext_vector_type(8)));
typedef _Float16 half2v __attribute__((ext_vector_type(2)));

// Paired dot: weights in [k/2][2N] interleave — wv0/wv1 = 8 outputs x k-pair.
// f16xf16 products are exact in f32; accumulation stays f32.
__device__ __forceinline__ void dot8p(float (&acc)[8], float4 wv0, float4 wv1,
                                      float a0, float a1) {
#if __has_builtin(__builtin_amdgcn_fdot2)
    const half2v ap = __builtin_bit_cast(half2v, __builtin_amdgcn_cvt_pkrtz(a0, a1));
    acc[0] = __builtin_amdgcn_fdot2(__builtin_bit_cast(half2v, wv0.x), ap, acc[0], false);
    acc[1] = __builtin_amdgcn_fdot2(__builtin_bit_cast(half2v, wv0.y), ap, acc[1], false);
    acc[2] = __builtin_amdgcn_fdot2(__builtin_bit_cast(half2v, wv0.z), ap, acc[2], false);
    acc[3] = __builtin_amdgcn_fdot2(__builtin_bit_cast(half2v, wv0.w), ap, acc[3], false);
    acc[4] = __builtin_amdgcn_fdot2(__builtin_bit_cast(half2v, wv1.x), ap, acc[4], false);
    acc[5] = __builtin_amdgcn_fdot2(__builtin_bit_cast(half2v, wv1.y), ap, acc[5], false);
    acc[6] = __builtin_amdgcn_fdot2(__builtin_bit_cast(half2v, wv1.z), ap, acc[6], false);
    acc[7] = __builtin_amdgcn_fdot2(__builtin_bit_cast(half2v, wv1.w), ap, acc[7], false);
#else
    half8v h0 = __builtin_bit_cast(half8v, wv0);
    half8v h1 = __builtin_bit_cast(half8v, wv1);
#pragma unroll
    for (int m = 0; m < 4; ++m) acc[m]     += (float)h0[2*m] * a0 + (float)h0[2*m+1] * a1;
#pragma unroll
    for (int m = 0; m < 4; ++m) acc[4 + m] += (float)h1[2*m] * a0 + (float)h1[2*m+1] * a1;
#endif
}

// lgkm-only barrier: drains LDS ops; global loads stay in flight across it.
#define BAR() do {                                   \
    __atomic_signal_fence(__ATOMIC_SEQ_CST);         \
    __builtin_amdgcn_s_waitcnt(0xC07F);              \
    __builtin_amdgcn_s_barrier();                    \
    __atomic_signal_fence(__ATOMIC_SEQ_CST);         \
} while (0)

// f32 [K][N] -> f16 paired layout: (k,j) -> (k>>1)*2N + 2j + (k&1).
__global__ void f2h_pair(const float* __restrict__ s, __half* __restrict__ d,
                         int K, int N) {
    int i = blockIdx.x * 256 + threadIdx.x;
    if (i < K * N) {
        int k = i / N, j = i - k * N;
        d[(size_t)(k >> 1) * (2 * N) + 2 * j + (k & 1)] = __float2half(s[i]);
    }
}

// ---------------------------------------------------------------------------
// Kernel 1: G = X @ W + bias
// ---------------------------------------------------------------------------
#define GT_M 128
#define GT_N 64
#define GT_K 16

__device__ __forceinline__ void stvec4(float* p, float4 v) { *(float4*)p = v; }
__device__ __forceinline__ void stvec4(__half* p, float4 v) {
    *(__half2*)p = __floats2half2_rn(v.x, v.y);
    *(__half2*)(p + 2) = __floats2half2_rn(v.z, v.w);
}

template <typename OT>
__global__ __launch_bounds__(256)
void xw_gemm(const float* __restrict__ X, const float* __restrict__ W,
             const float* __restrict__ bias, OT* __restrict__ G,
             int M, int N, int K) {
    __shared__ float As[GT_K][GT_M + 4];
    __shared__ float Bs[GT_K][GT_N];
    const int tid = threadIdx.x;
    const int bm = blockIdx.y * GT_M;
    const int bn = blockIdx.x * GT_N;
    const int tx = tid & 15;
    const int ty = tid >> 4;

    float acc[8][4];
#pragma unroll
    for (int i = 0; i < 8; ++i)
#pragma unroll
        for (int j = 0; j < 4; ++j) acc[i][j] = 0.f;

    for (int kt = 0; kt < K; kt += GT_K) {
#pragma unroll
        for (int i = 0; i < 8; ++i) {
            int idx = i * 256 + tid;
            int m = idx >> 4, k = idx & 15;
            int gk = kt + k;
            As[k][m] = (gk < K) ? X[(size_t)(bm + m) * K + gk] : 0.f;
        }
#pragma unroll
        for (int i = 0; i < 4; ++i) {
            int idx = i * 256 + tid;
            int k = idx >> 6, n = idx & 63;
            int gk = kt + k;
            Bs[k][n] = (gk < K) ? W[(size_t)gk * N + bn + n] : 0.f;
        }
        __syncthreads();
#pragma unroll
        for (int k = 0; k < GT_K; ++k) {
            float a[8], b[4];
            const float4 a0 = *(const float4*)&As[k][ty * 8];
            const float4 a1 = *(const float4*)&As[k][ty * 8 + 4];
            const float4 bv = *(const float4*)&Bs[k][tx * 4];
            a[0]=a0.x; a[1]=a0.y; a[2]=a0.z; a[3]=a0.w;
            a[4]=a1.x; a[5]=a1.y; a[6]=a1.z; a[7]=a1.w;
            b[0]=bv.x; b[1]=bv.y; b[2]=bv.z; b[3]=bv.w;
#pragma unroll
            for (int i = 0; i < 8; ++i)
#pragma unroll
                for (int j = 0; j < 4; ++j) acc[i][j] += a[i] * b[j];
        }
        __syncthreads();
    }
    const int n0 = bn + tx * 4;
#pragma unroll
    for (int i = 0; i < 8; ++i) {
        int m = bm + ty * 8 + i;
        float4 v;
        v.x = acc[i][0] + bias[n0 + 0];
        v.y = acc[i][1] + bias[n0 + 1];
        v.z = acc[i][2] + bias[n0 + 2];
        v.w = acc[i][3] + bias[n0 + 3];
        stvec4(&G[(size_t)m * N + n0], v);
    }
}

// ---------------------------------------------------------------------------
// Kernel 2: persistent recurrence. 256 blocks x 512 threads, 1 row/block.
// __launch_bounds__(512, 1). VGPR hard-capped at 128 (r1/r2/r4): no big
// register arrays; unroll streams are the pipeline.
// r5: block-staggered k-rotation (XCD-L2 burst de-contention) -> 3.63ms.
// r6/7: v_dot2_f32_f16 via paired [k/2][2N] weight layout — cuts the VALU
// op count of all matvec phases (8 fdot2 + 1 cvt_pkrtz per 8 outs x 2 k,
// vs 16 cvt + 16 fma). Same bytes streamed, f32 accumulation.
// att1 weights (96KB) + cw11/cw12 (16KB) pinned in LDS (paired layout).
// r8 (phase shuffle), r9 (1024thr), r10 (row-pairing) all REGRESSED and are
// reverted: per-phase stream time is bytes-bound with VALU nearly serial,
// and the 128-VGPR cap blocks deeper pipelining. This r7 form is the best
// measured state (marn_rec 2.84ms, total 3.20ms).
// ---------------------------------------------------------------------------
__global__ __launch_bounds__(512, 1)
void marn_rec(const float* __restrict__ G0, const __half* __restrict__ G1h,
              const __half* __restrict__ G2h,
              const __half* __restrict__ hU0, const __half* __restrict__ hV0,
              const __half* __restrict__ hU1, const __half* __restrict__ hV1,
              const __half* __restrict__ hU2, const __half* __restrict__ hV2,
              const __half* __restrict__ haw1, const float* __restrict__ ab1,
              const __half* __restrict__ haw2, const float* __restrict__ ab2,
              const __half* __restrict__ hcw10, const float* __restrict__ cb10,
              const float* __restrict__ cw20, const float* __restrict__ cb20,
              const __half* __restrict__ hcw11, const float* __restrict__ cb11,
              const float* __restrict__ cw21, const float* __restrict__ cb21,
              const __half* __restrict__ hcw12, const float* __restrict__ cb12,
              const float* __restrict__ cw22, const float* __restrict__ cb22,
              const float* __restrict__ fw1, const float* __restrict__ fb1,
              const float* __restrict__ fw2, const float* __restrict__ fb2,
              float* __restrict__ out) {
    __shared__ float hz[256];     // [h0(128)|h1(32)|h2(32)|z(64)]
    __shared__ float cst[192];
    __shared__ float a1s[256];
    __shared__ float attE[768];
    __shared__ float hid[128];
    __shared__ float rinv[4];     // reciprocal softmax denominators
    __shared__ float scratch[3840];
    __shared__ float c2w[3072];   // cw20(2048)|cw21(512)|cw22(512)
    __shared__ __align__(16) __half s_aw1[49152];  // att1 weights, paired, pinned
    __shared__ __align__(16) __half s_c1b[8192];   // cw11(4096)|cw12(4096), paired

    const int tid = threadIdx.x;
    const int row = blockIdx.x;
    // de-contention rotation offsets, in k-PAIRS (r5 mechanism)
    const int rotPA = ((row >> 3) & 3) * 4;   // stage A: 16 pairs
    const int rotPB = ((row >> 3) & 7) * 4;   // att2:    32 pairs
    const int rotPC = ((row >> 3) & 3) * 4;   // comp1:   16 pairs

    for (int i = tid; i < 256; i += 512) hz[i] = 0.f;
    if (tid < 192) cst[tid] = 0.f;
    for (int i = tid; i < 2048; i += 512) c2w[i] = cw20[i];
    if (tid < 512) { c2w[2048 + tid] = cw21[tid]; c2w[2560 + tid] = cw22[tid]; }
    {
        const float4* s4 = (const float4*)haw1;
        float4* d4 = (float4*)s_aw1;
        for (int i = tid; i < 6144; i += 512) d4[i] = s4[i];
        float4* d1 = (float4*)s_c1b;
        d1[tid] = ((const float4*)hcw11)[tid];
        d1[512 + tid] = ((const float4*)hcw12)[tid];
    }
    __syncthreads();

    // ---- stage A mapping (480 active), paired layout ----
    const __half* WBa = nullptr; int HOa = 0, STRa = 0, SOa = 0;
    if (tid < 384) {
        const int g = tid & 63, kc = tid >> 6;   // kc 0..5
        const int cb = g * 8;
        if (kc < 4) { WBa = hU0 + (size_t)(16 * kc) * 1024 + 2 * cb; HOa = 32 * kc; }
        else        { WBa = hV0 + (size_t)(16 * (kc - 4)) * 1024 + 2 * cb; HOa = 192 + 32 * (kc - 4); }
        STRa = 1024;                             // halfs per k-pair row
        SOa = kc * 512 + cb;
    } else if (tid < 480) {
        const int u = tid - 384;                 // 0..95
        const int kc = u >> 5;                   // 0..2
        const int g2 = u & 31;
        const int cell = g2 >> 4;
        const int cb = (g2 & 15) * 8;
        const __half* Uc = cell ? hU2 : hU1;
        const __half* Vc = cell ? hV2 : hV1;
        if (kc == 0) { WBa = Uc + 2 * cb; HOa = 128 + 32 * cell; }
        else         { WBa = Vc + (size_t)(16 * (kc - 1)) * 256 + 2 * cb; HOa = 192 + 32 * (kc - 1); }
        STRa = 256;
        SOa = 3072 + kc * 256 + cell * 128 + cb;
    }
    // ---- att1 mapping (256 active), weights in LDS (paired) ----
    int AW1o = 0, HO1 = 0, SO1 = 0;
    if (tid < 256) {
        const int g = tid & 31, kc = tid >> 5;   // kc 0..7
        const int cb = g * 8;
        AW1o = kc * 6144 + 2 * cb;               // paired: pair stride 512
        HO1 = 24 * kc;
        SO1 = kc * 256 + cb;
    }
    // ---- att2 mapping (384 active), paired ----
    const int kc2 = tid / 96;
    const int g2a = tid - kc2 * 96;
    const __half* WB2 = haw2 + (size_t)(32 * kc2) * 1536 + 2 * (g2a * 8);
    const int HO2 = 64 * kc2;
    const int SO2 = kc2 * 768 + g2a * 8;
    // ---- comp1 mapping (192 active), att_out fused, paired ----
    const __half* WBc = nullptr; int HOc = 0, SOc = 0, C1o = 0, HSELo = 0, HSELm = 0, HBc = 0;
    if (tid < 128) {
        const int g = tid & 7, kc = tid >> 3;    // kc 0..15
        WBc = hcw10 + (size_t)(16 * kc) * 128 + 2 * (g * 8);
        HOc = 32 * kc;
        SOc = kc * 64 + g * 8;
        HSELo = 0; HSELm = 127; HBc = 0;
    } else if (tid < 192) {
        const int u = tid - 128;                 // 0..63
        const int cell = u >> 5;
        const int rem = u & 31;
        const int g = rem & 3, kc = rem >> 2;    // kc 0..7
        C1o = cell * 4096 + kc * 512 + 2 * (g * 8);  // paired: pair stride 64
        HOc = 512 + 128 * cell + 16 * kc;
        SOc = 1024 + cell * 256 + kc * 32 + g * 8;
        HSELo = 128 + 32 * cell; HSELm = 31; HBc = 512 + 128 * cell;
    }
    const int AHc = HOc / 192;                   // head idx (chunks never cross heads)
    // ---- gates / G-prefetch mapping (192 active) ----
    const int g12_cell = ((tid - 128) >> 5) & 1;
    const int g12_uu   = (tid - 128) & 31;

    float  g0p[4];
    __half g12p[4];
    if (tid < 128) {
        const float* gp = G0 + ((size_t)row * TT + 0) * 512;
#pragma unroll
        for (int q = 0; q < 4; ++q) g0p[q] = gp[q * 128 + tid];
    } else if (tid < 192) {
        const __half* gp = (g12_cell ? G2h : G1h) + ((size_t)row * TT + 0) * 128;
#pragma unroll
        for (int q = 0; q < 4; ++q) g12p[q] = gp[q * 32 + g12_uu];
    }

    for (int t = 0; t < TT; ++t) {
        // ======== stage A compute (L2 stream, paired dot2, rotated) ========
        if (tid < 480) {
            float acc[8];
#pragma unroll
            for (int j = 0; j < 8; ++j) acc[j] = 0.f;
#pragma unroll 8
            for (int p = 0; p < 16; ++p) {
                const int kk = (p + rotPA) & 15;
                const __half* wp = WBa + (size_t)kk * STRa;
                dot8p(acc, *(const float4*)wp, *(const float4*)(wp + 8),
                      hz[HOa + 2 * kk], hz[HOa + 2 * kk + 1]);
            }
            float* s0 = &scratch[SOa];
            *(float4*)s0       = make_float4(acc[0], acc[1], acc[2], acc[3]);
            *(float4*)(s0 + 4) = make_float4(acc[4], acc[5], acc[6], acc[7]);
        }
        BAR();
        // ======== gates ========
        if (tid < 128) {
            float s[4];
#pragma unroll
            for (int q = 0; q < 4; ++q) {
                const int c4 = q * 128 + tid;
                float v = g0p[q];
#pragma unroll
                for (int kc = 0; kc < 6; ++kc) v += scratch[kc * 512 + c4];
                s[q] = v;
            }
            const float f  = sigf(s[0]);
            const float ig = sigf(s[1]);
            const float o  = sigf(s[2]);
            const float ch = tanhf(s[3]);
            const float c = f * cst[tid] + ig * ch;
            cst[tid] = c;
            hz[tid] = tanhf(c) * o;
        } else if (tid < 192) {
            const int cell = g12_cell, uu = g12_uu;
            float s[4];
#pragma unroll
            for (int q = 0; q < 4; ++q) {
                float v = __half2float(g12p[q]);
#pragma unroll
                for (int kc = 0; kc < 3; ++kc)
                    v += scratch[3072 + kc * 256 + cell * 128 + q * 32 + uu];
                s[q] = v;
            }
            const float f  = sigf(s[0]);
            const float ig = sigf(s[1]);
            const float o  = sigf(s[2]);
            const float ch = tanhf(s[3]);
            const int si = 128 + 32 * cell + uu;
            const float c = f * cst[si] + ig * ch;
            cst[si] = c;
            hz[si] = tanhf(c) * o;
        }
        BAR();
        // ======== att1 compute (weights in LDS, paired dot2) ========
        if (tid < 256) {
            float acc[8];
#pragma unroll
            for (int j = 0; j < 8; ++j) acc[j] = 0.f;
            const __half* wp = &s_aw1[AW1o];
#pragma unroll
            for (int p = 0; p < 12; ++p)
                dot8p(acc, *(const float4*)(wp + p * 512), *(const float4*)(wp + p * 512 + 8),
                      hz[HO1 + 2 * p], hz[HO1 + 2 * p + 1]);
            float* s0 = &scratch[SO1];
            *(float4*)s0       = make_float4(acc[0], acc[1], acc[2], acc[3]);
            *(float4*)(s0 + 4) = make_float4(acc[4], acc[5], acc[6], acc[7]);
        }
        BAR();
        // ======== att1 reduce + relu ========
        if (tid < 256) {
            float s = ab1[tid];
#pragma unroll
            for (int kc = 0; kc < 8; ++kc) s += scratch[kc * 256 + tid];
            a1s[tid] = fmaxf(s, 0.f);
        }
        BAR();
        // ======== att2 compute (L2 stream, paired dot2, rotated) ========
        if (tid < 384) {
            float acc[8];
#pragma unroll
            for (int j = 0; j < 8; ++j) acc[j] = 0.f;
#pragma unroll 8
            for (int p = 0; p < 32; ++p) {
                const int kk = (p + rotPB) & 31;
                const __half* wp = WB2 + (size_t)kk * 1536;
                dot8p(acc, *(const float4*)wp, *(const float4*)(wp + 8),
                      a1s[HO2 + 2 * kk], a1s[HO2 + 2 * kk + 1]);
            }
            float* s0 = &scratch[SO2];
            *(float4*)s0       = make_float4(acc[0], acc[1], acc[2], acc[3]);
            *(float4*)(s0 + 4) = make_float4(acc[4], acc[5], acc[6], acc[7]);
        }
        BAR();
        // ======== att2 reduce + sigmoid + exp ========
#pragma unroll
        for (int i = 0; i < 2; ++i) {
            const int idx = i * 512 + tid;
            if (idx < 768) {
                float s = ab2[idx];
#pragma unroll
                for (int kc = 0; kc < 4; ++kc) s += scratch[kc * 768 + idx];
                attE[idx] = expf(sigf(s));
            }
        }
        BAR();
        // ======== softmax reciprocal denominators ========
        if (tid < 256) {
            const int a = tid >> 6, lane = tid & 63;
            float v = attE[a * 192 + lane] + attE[a * 192 + 64 + lane]
                    + attE[a * 192 + 128 + lane];
#pragma unroll
            for (int s = 32; s >= 1; s >>= 1) v += __shfl_xor(v, s);
            if (lane == 0) rinv[a] = 1.f / v;
        }
        BAR();
        // ======== comp1 compute (att_out fused, paired dot2) ========
        if (tid < 192) {
            const float ri = rinv[AHc];
            float acc[8];
#pragma unroll
            for (int j = 0; j < 8; ++j) acc[j] = 0.f;
            if (tid < 128) {
#pragma unroll 8
                for (int p = 0; p < 16; ++p) {
                    const int kk = (p + rotPC) & 15;
                    const int i0 = HOc + 2 * kk;
                    const float a0 = attE[i0] * ri * hz[i0 & 127];
                    const float a1 = attE[i0 + 1] * ri * hz[(i0 + 1) & 127];
                    const __half* wp = WBc + (size_t)kk * 128;
                    dot8p(acc, *(const float4*)wp, *(const float4*)(wp + 8), a0, a1);
                }
            } else {
                const __half* wp = &s_c1b[C1o];
#pragma unroll
                for (int p = 0; p < 8; ++p) {
                    const int i0 = HOc + 2 * p;
                    const float a0 = attE[i0] * ri * hz[HSELo + ((i0 - HBc) & HSELm)];
                    const float a1 = attE[i0 + 1] * ri * hz[HSELo + ((i0 + 1 - HBc) & HSELm)];
                    dot8p(acc, *(const float4*)(wp + p * 64), *(const float4*)(wp + p * 64 + 8),
                          a0, a1);
                }
            }
            float* s0 = &scratch[SOc];
            *(float4*)s0       = make_float4(acc[0], acc[1], acc[2], acc[3]);
            *(float4*)(s0 + 4) = make_float4(acc[4], acc[5], acc[6], acc[7]);
        }
        BAR();
        // ======== comp1 reduce + relu ========
        if (tid < 128) {
            float s;
            if (tid < 64) {
                s = cb10[tid];
#pragma unroll
                for (int kc = 0; kc < 16; ++kc) s += scratch[kc * 64 + tid];
            } else {
                const int cc = tid - 64;
                const int cell = cc >> 5, j = cc & 31;
                s = (cell ? cb12 : cb11)[j];
#pragma unroll
                for (int kc = 0; kc < 8; ++kc)
                    s += scratch[1024 + cell * 256 + kc * 32 + j];
            }
            hid[tid] = fmaxf(s, 0.f);
        }
        BAR();
        // ======== comp2 + z softmax (one wave) ========
        if (tid < 64) {
            const int j = tid;
            float acc;
            if (j < 32) {
                acc = cb20[j];
#pragma unroll
                for (int k = 0; k < 64; ++k) acc += hid[k] * c2w[k * 32 + j];
            } else if (j < 48) {
                const int o = j - 32; acc = cb21[o];
#pragma unroll
                for (int k = 0; k < 32; ++k) acc += hid[64 + k] * c2w[2048 + k * 16 + o];
            } else {
                const int o = j - 48; acc = cb22[o];
#pragma unroll
                for (int k = 0; k < 32; ++k) acc += hid[96 + k] * c2w[2560 + k * 16 + o];
            }
            const float e = expf(sigf(acc));
            float v = e;
#pragma unroll
            for (int s = 32; s >= 1; s >>= 1) v += __shfl_xor(v, s);
            hz[192 + j] = e / v;
        }
        // ======== G prefetch for t+1 (stays in flight across BAR) ========
        {
            const int tn = (t + 1 < TT) ? t + 1 : TT - 1;
            if (tid < 128) {
                const float* gp = G0 + ((size_t)row * TT + tn) * 512;
#pragma unroll
                for (int q = 0; q < 4; ++q) g0p[q] = gp[q * 128 + tid];
            } else if (tid < 192) {
                const __half* gp = (g12_cell ? G2h : G1h) + ((size_t)row * TT + tn) * 128;
#pragma unroll
                for (int q = 0; q < 4; ++q) g12p[q] = gp[q * 32 + g12_uu];
            }
        }
        BAR();
    }

    __syncthreads();
    // ======== final MLP ========
    if (tid < 64) {
        const int j = tid;
        float acc = fb1[j];
#pragma unroll 8
        for (int k = 0; k < 64; ++k)  acc += hz[192 + k] * fw1[k * 64 + j];
#pragma unroll 8
        for (int k = 0; k < 192; ++k) acc += hz[k] * fw1[(64 + k) * 64 + j];
        hid[j] = fmaxf(acc, 0.f);
    }
    __syncthreads();
    if (tid < 64) {
        float v = hid[tid] * fw2[tid];
#pragma unroll
        for (int s = 32; s >= 1; s >>= 1) v += __shfl_xor(v, s);
        if (tid == 0) out[row] = v + fb2[0];
    }
}

// ---------------------------------------------------------------------------
extern "C" void kernel_launch(void* const* d_in, const int* in_sizes, int n_in,
                              void* d_out, int out_size, void* d_ws, size_t ws_size,
                              hipStream_t stream) {
    const float* x0   = (const float*)d_in[0];
    const float* x1   = (const float*)d_in[1];
    const float* x2   = (const float*)d_in[2];
    const float* W0   = (const float*)d_in[3];
    const float* U0   = (const float*)d_in[4];
    const float* V0   = (const float*)d_in[5];
    const float* b0   = (const float*)d_in[6];
    const float* W1   = (const float*)d_in[7];
    const float* U1   = (const float*)d_in[8];
    const float* V1   = (const float*)d_in[9];
    const float* b1   = (const float*)d_in[10];
    const float* W2   = (const float*)d_in[11];
    const float* U2   = (const float*)d_in[12];
    const float* V2   = (const float*)d_in[13];
    const float* b2   = (const float*)d_in[14];
    const float* aw1  = (const float*)d_in[15];
    const float* ab1  = (const float*)d_in[16];
    const float* aw2  = (const float*)d_in[17];
    const float* ab2  = (const float*)d_in[18];
    const float* cw10 = (const float*)d_in[19];
    const float* cb10 = (const float*)d_in[20];
    const float* cw20 = (const float*)d_in[21];
    const float* cb20 = (const float*)d_in[22];
    const float* cw11 = (const float*)d_in[23];
    const float* cb11 = (const float*)d_in[24];
    const float* cw21 = (const float*)d_in[25];
    const float* cb21 = (const float*)d_in[26];
    const float* cw12 = (const float*)d_in[27];
    const float* cb12 = (const float*)d_in[28];
    const float* cw22 = (const float*)d_in[29];
    const float* cb22 = (const float*)d_in[30];
    const float* fw1  = (const float*)d_in[31];
    const float* fb1  = (const float*)d_in[32];
    const float* fw2  = (const float*)d_in[33];
    const float* fb2  = (const float*)d_in[34];
    float* out = (float*)d_out;

    const size_t M = (size_t)BB * TT;   // 65536

    float*  G0  = (float*)d_ws;                 // M*512 f32
    __half* G1h = (__half*)(G0 + M * 512);      // M*128 f16
    __half* G2h = G1h + M * 128;                // M*128 f16
    __half* hU0   = G2h + M * 128;              // paired layouts below
    __half* hV0   = hU0 + 65536;
    __half* hU1   = hV0 + 32768;
    __half* hV1   = hU1 + 4096;
    __half* hU2   = hV1 + 8192;
    __half* hV2   = hU2 + 4096;
    __half* haw1  = hV2 + 8192;
    __half* haw2  = haw1 + 49152;
    __half* hcw10 = haw2 + 196608;
    __half* hcw11 = hcw10 + 32768;
    __half* hcw12 = hcw11 + 4096;

    f2h_pair<<<(65536 + 255) / 256, 256, 0, stream>>>(U0, hU0, 128, 512);
    f2h_pair<<<(32768 + 255) / 256, 256, 0, stream>>>(V0, hV0, 64, 512);
    f2h_pair<<<(4096 + 255) / 256, 256, 0, stream>>>(U1, hU1, 32, 128);
    f2h_pair<<<(8192 + 255) / 256, 256, 0, stream>>>(V1, hV1, 64, 128);
    f2h_pair<<<(4096 + 255) / 256, 256, 0, stream>>>(U2, hU2, 32, 128);
    f2h_pair<<<(8192 + 255) / 256, 256, 0, stream>>>(V2, hV2, 64, 128);
    f2h_pair<<<(49152 + 255) / 256, 256, 0, stream>>>(aw1, haw1, 192, 256);
    f2h_pair<<<(196608 + 255) / 256, 256, 0, stream>>>(aw2, haw2, 256, 768);
    f2h_pair<<<(32768 + 255) / 256, 256, 0, stream>>>(cw10, hcw10, 512, 64);
    f2h_pair<<<(4096 + 255) / 256, 256, 0, stream>>>(cw11, hcw11, 128, 32);
    f2h_pair<<<(4096 + 255) / 256, 256, 0, stream>>>(cw12, hcw12, 128, 32);

    xw_gemm<float><<<dim3(512 / GT_N, M / GT_M), 256, 0, stream>>>(x0, W0, b0, G0, (int)M, 512, 300);
    xw_gemm<__half><<<dim3(128 / GT_N, M / GT_M), 256, 0, stream>>>(x1, W1, b1, G1h, (int)M, 128, 74);
    xw_gemm<__half><<<dim3(128 / GT_N, M / GT_M), 256, 0, stream>>>(x2, W2, b2, G2h, (int)M, 128, 35);

    // 256 blocks x 512 threads, 1 row/block
    marn_rec<<<256, 512, 0, stream>>>(G0, G1h, G2h, hU0, hV0, hU1, hV1, hU2, hV2,
                                      haw1, ab1, haw2, ab2,
                                      hcw10, cb10, cw20, cb20,
                                      hcw11, cb11, cw21, cb21,
                                      hcw12, cb12, cw22, cb22,
                                      fw1, fb1, fw2, fb2, out);
}